// Round 10
// baseline (1833.785 us; speedup 1.0000x reference)
//
#include <hip/hip_runtime.h>

#define EPSILON 1e-6f
#define NADMIN 256
#define NBATCH 16
#define NPIX (1024 * 1024)
#define NV (NPIX / 4)          // 262144 float4 per batch

#define APPLY_BLOCKS 512
#define SEG_BLOCKS 256
#define RED_BLOCKS NBATCH
#define TOTAL_BLOCKS (APPLY_BLOCKS + SEG_BLOCKS + RED_BLOCKS)  // 784 <= 1024 slots
#define THREADS 512

#define NCOPY 8
#define HSTRIDE 257
#define SCALE 65536.0f
#define SPIN_GUARD (1 << 21)

// d_ws layout (u32 units)
#define SPART_OFF 0u                       // u32[16][256][256] = 4 MB
#define R_OFF     (16u * 256u * 256u)      // f32[16][256]
#define DONE_OFF  (R_OFF + 16u * 256u)     // u32[16]
#define RFLAG_OFF (DONE_OFF + 16u)         // u32[16]
#define WS_U32_NEEDED (RFLAG_OFF + 16u)

__global__ __launch_bounds__(64) void zero_flags_kernel(unsigned int* __restrict__ W)
{
    int i = threadIdx.x;
    if (i < 32) W[DONE_OFF + i] = 0u;      // done[16] + rflag[16] (adjacent)
}

// ---------------------------------------------------------------------------
// Fused pipelined kernel: 784 co-resident blocks, role by blockIdx.x.
//  [0,512)    apply:  per batch b (in order): spin rflag[b] (LOAD-only+sleep),
//                     load R, process 512 float4 (1/thread).
//  [512,768)  segsum: per batch b (in order): LDS u32 histogram of its 1024-
//                     float4 slice, plain-store partials to Spart[b][sid][*],
//                     fence, release-add done[b].
//  [768,784)  reduce: b = x-768: spin done[b]==256, sum Spart (u64, fixed
//                     order), R[b]=census/(S+eps), fence, release rflag[b].
// Pipelining: batch b's segsum completes ~b*3us; apply/reduce trail it, so
// the DS pipe (segsum) and memory fabric (apply) overlap across batches.
// All sync is load-poll (r8's failure was RMW-polling). Exact u32 math ->
// deterministic across replays. Bounded spins -> no hang; stale flags in a
// solo replay fall through.
// ---------------------------------------------------------------------------
__global__ __launch_bounds__(THREADS, 8) void fused_kernel(
    const float* __restrict__ P,
    const int* __restrict__ ids,
    const float* __restrict__ census,
    unsigned int* __restrict__ W,
    float* __restrict__ out)
{
    unsigned int* Spart = W + SPART_OFF;
    float*        R     = (float*)(W + R_OFF);
    unsigned int* done  = W + DONE_OFF;
    unsigned int* rflag = W + RFLAG_OFF;

    const int x = blockIdx.x;
    const int t = threadIdx.x;

    if (x < APPLY_BLOCKS) {
        // ---------------- APPLY ----------------
        __shared__ float s_R[NADMIN];
        const int aid = x;
        for (int b = 0; b < NBATCH; ++b) {
            if (t == 0) {
                int g = 0;
                while (__hip_atomic_load(&rflag[b], __ATOMIC_ACQUIRE,
                                         __HIP_MEMORY_SCOPE_AGENT) == 0u &&
                       ++g < SPIN_GUARD)
                    __builtin_amdgcn_s_sleep(2);
            }
            __syncthreads();                       // all threads past batch b-1
            if (t < NADMIN)
                s_R[t] = __hip_atomic_load(&R[b * NADMIN + t], __ATOMIC_RELAXED,
                                           __HIP_MEMORY_SCOPE_AGENT);
            __syncthreads();

            const int i = aid * (NV / APPLY_BLOCKS) + t;   // 512 f4/block
            const float4* p4 = (const float4*)(P   + (size_t)b * NPIX);
            const int4*  id4 = (const int4*)  (ids + (size_t)b * NPIX);
            float4*       o4 = (float4*)(out + (size_t)b * NPIX);
            float4 p = p4[i];
            int4   d = id4[i];
            float4 o;
            o.x = (d.x >= 0) ? p.x * s_R[d.x] : p.x;
            o.y = (d.y >= 0) ? p.y * s_R[d.y] : p.y;
            o.z = (d.z >= 0) ? p.z * s_R[d.z] : p.z;
            o.w = (d.w >= 0) ? p.w * s_R[d.w] : p.w;
            o4[i] = o;
        }
    } else if (x < APPLY_BLOCKS + SEG_BLOCKS) {
        // ---------------- SEGSUM ----------------
        __shared__ unsigned int hist[NCOPY * HSTRIDE];
        const int sid = x - APPLY_BLOCKS;
        for (int i = t; i < NCOPY * HSTRIDE; i += THREADS) hist[i] = 0u;
        __syncthreads();
        unsigned int* __restrict__ h = hist + (t & (NCOPY - 1)) * HSTRIDE;

        for (int b = 0; b < NBATCH; ++b) {
            const float4* p4 = (const float4*)(P   + (size_t)b * NPIX);
            const int4*  id4 = (const int4*)  (ids + (size_t)b * NPIX);
            const int i0 = sid * (NV / SEG_BLOCKS) + t;    // 1024 f4/block
            const int i1 = i0 + THREADS;
            float4 pa = p4[i0]; int4 da = id4[i0];         // all loads first
            float4 pb = p4[i1]; int4 db = id4[i1];
            if (da.x >= 0) atomicAdd(&h[da.x], __float2uint_rn(pa.x * SCALE));
            if (da.y >= 0) atomicAdd(&h[da.y], __float2uint_rn(pa.y * SCALE));
            if (da.z >= 0) atomicAdd(&h[da.z], __float2uint_rn(pa.z * SCALE));
            if (da.w >= 0) atomicAdd(&h[da.w], __float2uint_rn(pa.w * SCALE));
            if (db.x >= 0) atomicAdd(&h[db.x], __float2uint_rn(pb.x * SCALE));
            if (db.y >= 0) atomicAdd(&h[db.y], __float2uint_rn(pb.y * SCALE));
            if (db.z >= 0) atomicAdd(&h[db.z], __float2uint_rn(pb.z * SCALE));
            if (db.w >= 0) atomicAdd(&h[db.w], __float2uint_rn(pb.w * SCALE));
            __syncthreads();                       // atomics done

            if (t < NADMIN) {
                unsigned int s = 0u;
                #pragma unroll
                for (int c = 0; c < NCOPY; ++c) s += hist[c * HSTRIDE + t];
                Spart[((size_t)b * SEG_BLOCKS + sid) * NADMIN + t] = s;
            }
            __threadfence();
            __syncthreads();                       // flush reads + stores done
            if (t == 0)
                __hip_atomic_fetch_add(&done[b], 1u, __ATOMIC_RELEASE,
                                       __HIP_MEMORY_SCOPE_AGENT);
            for (int i = t; i < NCOPY * HSTRIDE; i += THREADS) hist[i] = 0u;
            __syncthreads();                       // hist clean for next batch
        }
    } else {
        // ---------------- REDUCE ----------------
        const int b = x - (APPLY_BLOCKS + SEG_BLOCKS);
        if (t == 0) {
            int g = 0;
            while (__hip_atomic_load(&done[b], __ATOMIC_ACQUIRE,
                                     __HIP_MEMORY_SCOPE_AGENT) < SEG_BLOCKS &&
                   ++g < SPIN_GUARD)
                __builtin_amdgcn_s_sleep(2);
        }
        __syncthreads();
        if (t < NADMIN) {
            unsigned long long total = 0ull;
            const unsigned int* base = Spart + (size_t)b * SEG_BLOCKS * NADMIN + t;
            for (int j = 0; j < SEG_BLOCKS; ++j)
                total += __hip_atomic_load(&base[(size_t)j * NADMIN],
                                           __ATOMIC_RELAXED,
                                           __HIP_MEMORY_SCOPE_AGENT);
            float S = (float)((double)total * (1.0 / SCALE));
            R[b * NADMIN + t] = census[b * NADMIN + t] / (S + EPSILON);
        }
        __threadfence();
        __syncthreads();
        if (t == 0)
            __hip_atomic_store(&rflag[b], 1u, __ATOMIC_RELEASE,
                               __HIP_MEMORY_SCOPE_AGENT);
    }
}

// ======================= fallback: known-good r9 path =======================
#define FB_SEG_BLOCKS 64
#define FB_SEG_THREADS 512
#define FB_UNROLL 4

__global__ __launch_bounds__(FB_SEG_THREADS) void fb_segsum_kernel(
    const float* __restrict__ P, const int* __restrict__ ids,
    unsigned int* __restrict__ Spart)
{
    __shared__ unsigned int hist[NCOPY * HSTRIDE];
    const int b = blockIdx.y, t = threadIdx.x;
    for (int i = t; i < NCOPY * HSTRIDE; i += FB_SEG_THREADS) hist[i] = 0u;
    __syncthreads();
    unsigned int* __restrict__ h = hist + (t & (NCOPY - 1)) * HSTRIDE;
    const float4* p4 = (const float4*)(P + (size_t)b * NPIX);
    const int4*  id4 = (const int4*)(ids + (size_t)b * NPIX);
    const int stride = gridDim.x * blockDim.x;
    int i = blockIdx.x * blockDim.x + t;
    for (; i + (FB_UNROLL - 1) * stride < NV; i += FB_UNROLL * stride) {
        float4 p[FB_UNROLL]; int4 d[FB_UNROLL];
        #pragma unroll
        for (int u = 0; u < FB_UNROLL; ++u) { p[u] = p4[i + u * stride]; d[u] = id4[i + u * stride]; }
        #pragma unroll
        for (int u = 0; u < FB_UNROLL; ++u) {
            if (d[u].x >= 0) atomicAdd(&h[d[u].x], __float2uint_rn(p[u].x * SCALE));
            if (d[u].y >= 0) atomicAdd(&h[d[u].y], __float2uint_rn(p[u].y * SCALE));
            if (d[u].z >= 0) atomicAdd(&h[d[u].z], __float2uint_rn(p[u].z * SCALE));
            if (d[u].w >= 0) atomicAdd(&h[d[u].w], __float2uint_rn(p[u].w * SCALE));
        }
    }
    __syncthreads();
    if (t < NADMIN) {
        unsigned int s = 0u;
        #pragma unroll
        for (int c = 0; c < NCOPY; ++c) s += hist[c * HSTRIDE + t];
        Spart[((size_t)b * FB_SEG_BLOCKS + blockIdx.x) * NADMIN + t] = s;
    }
}

__global__ __launch_bounds__(NADMIN) void fb_reduce_kernel(
    const unsigned int* __restrict__ Spart, const float* __restrict__ census,
    float* __restrict__ R)
{
    const int b = blockIdx.x, a = threadIdx.x;
    const unsigned int* base = Spart + (size_t)b * FB_SEG_BLOCKS * NADMIN + a;
    unsigned long long total = 0ull;
    #pragma unroll 8
    for (int j = 0; j < FB_SEG_BLOCKS; ++j) total += base[j * NADMIN];
    float S = (float)((double)total * (1.0 / SCALE));
    R[b * NADMIN + a] = census[b * NADMIN + a] / (S + EPSILON);
}

__global__ __launch_bounds__(256) void fb_apply_kernel(
    const float* __restrict__ P, const int* __restrict__ ids,
    const float* __restrict__ R, float* __restrict__ out)
{
    __shared__ float s_R[NADMIN];
    const int b = blockIdx.y, t = threadIdx.x;
    if (t < NADMIN) s_R[t] = R[b * NADMIN + t];
    __syncthreads();
    const float4* p4 = (const float4*)(P + (size_t)b * NPIX);
    const int4*  id4 = (const int4*)(ids + (size_t)b * NPIX);
    float4* o4 = (float4*)(out + (size_t)b * NPIX);
    const int stride = gridDim.x * blockDim.x;
    for (int i = blockIdx.x * blockDim.x + t; i < NV; i += stride) {
        float4 p = p4[i]; int4 d = id4[i]; float4 o;
        o.x = (d.x >= 0) ? p.x * s_R[d.x] : p.x;
        o.y = (d.y >= 0) ? p.y * s_R[d.y] : p.y;
        o.z = (d.z >= 0) ? p.z * s_R[d.z] : p.z;
        o.w = (d.w >= 0) ? p.w * s_R[d.w] : p.w;
        o4[i] = o;
    }
}

extern "C" void kernel_launch(void* const* d_in, const int* in_sizes, int n_in,
                              void* d_out, int out_size, void* d_ws, size_t ws_size,
                              hipStream_t stream)
{
    const float* P      = (const float*)d_in[0];
    const int*   ids    = (const int*)d_in[1];
    const float* census = (const float*)d_in[2];
    float* out = (float*)d_out;
    unsigned int* W = (unsigned int*)d_ws;

    if (ws_size >= (size_t)WS_U32_NEEDED * 4u) {
        zero_flags_kernel<<<1, 64, 0, stream>>>(W);
        fused_kernel<<<dim3(TOTAL_BLOCKS), dim3(THREADS), 0, stream>>>(
            P, ids, census, W, out);
    } else {
        // deterministic fallback (round-9 structure, 75 us)
        unsigned int* Spart = W;
        float* R = (float*)(Spart + (size_t)NBATCH * FB_SEG_BLOCKS * NADMIN);
        fb_segsum_kernel<<<dim3(FB_SEG_BLOCKS, NBATCH), dim3(FB_SEG_THREADS), 0, stream>>>(P, ids, Spart);
        fb_reduce_kernel<<<dim3(NBATCH), dim3(NADMIN), 0, stream>>>(Spart, census, R);
        fb_apply_kernel<<<dim3(128, NBATCH), dim3(256), 0, stream>>>(P, ids, R, out);
    }
}

// Round 11
// 79.335 us; speedup vs baseline: 23.1144x; 23.1144x over previous
//
#include <hip/hip_runtime.h>

#define EPSILON 1e-6f
#define NADMIN 256
#define NBATCH 16
#define NPIX (1024 * 1024)    // H*W per batch
#define SEG_BLOCKS 64         // segsum blocks per batch
#define SEG_THREADS 512
#define NCOPY 32              // one copy per bank: addr = bin*32 + (lane&31)
                              // -> bank = lane&31, conflict-free BY CONSTRUCTION.
                              // (r9's (lane&7)*257 left bank = bin+lane&7 = random;
                              // bank conflicts were never actually eliminated in
                              // any u32-atomic round — this is the open hypothesis.)
#define UNROLL 4
#define SCALE 65536.0f        // fixed-point scale (p in [0,1))

// ---------------------------------------------------------------------------
// Pass 1: per-batch partial segment sums, fixed-point u32, native ds_add_u32.
// hist[bin][copy=lane&31]: every lane's atomic lands in its own bank; same-
// address collisions only between lanes 32 apart with equal bin (p~1/256).
// 32 KB LDS, 512 thr -> 4 blocks/CU = 32 waves = 100% occupancy (wave-limited).
// grid = (SEG_BLOCKS, NBATCH), block = 512 -> 8 iters/thread.
// Max cell value: 16 same-copy threads x 32 px x 65535 < 2^25; block total
// 16384 px x 2^16 = 2^30 < 2^32. Exact integer math -> replay-deterministic.
// ---------------------------------------------------------------------------
__global__ __launch_bounds__(SEG_THREADS) void segsum_kernel(
    const float* __restrict__ P,
    const int* __restrict__ ids,
    unsigned int* __restrict__ Spart)
{
    __shared__ unsigned int hist[NADMIN * NCOPY];   // 32 KB
    const int b = blockIdx.y;
    const int t = threadIdx.x;

    for (int i = t; i < NADMIN * NCOPY; i += SEG_THREADS) hist[i] = 0u;
    __syncthreads();

    const int copy = t & 31;

    const float4* __restrict__ p4  = (const float4*)(P   + (size_t)b * NPIX);
    const int4*   __restrict__ id4 = (const int4*)  (ids + (size_t)b * NPIX);
    const int nvec = NPIX / 4;                      // 262144
    const int stride = gridDim.x * blockDim.x;      // 32768

    int i = blockIdx.x * blockDim.x + t;
    for (; i + (UNROLL - 1) * stride < nvec; i += UNROLL * stride) {
        float4 p[UNROLL];
        int4   d[UNROLL];
        #pragma unroll
        for (int u = 0; u < UNROLL; ++u) {          // issue all loads first
            p[u] = p4[i + u * stride];
            d[u] = id4[i + u * stride];
        }
        #pragma unroll
        for (int u = 0; u < UNROLL; ++u) {          // bank-aligned ds_add_u32
            if (d[u].x >= 0) atomicAdd(&hist[d[u].x * NCOPY + copy], __float2uint_rn(p[u].x * SCALE));
            if (d[u].y >= 0) atomicAdd(&hist[d[u].y * NCOPY + copy], __float2uint_rn(p[u].y * SCALE));
            if (d[u].z >= 0) atomicAdd(&hist[d[u].z * NCOPY + copy], __float2uint_rn(p[u].z * SCALE));
            if (d[u].w >= 0) atomicAdd(&hist[d[u].w * NCOPY + copy], __float2uint_rn(p[u].w * SCALE));
        }
    }
    for (; i < nvec; i += stride) {                 // tail (empty here)
        float4 p = p4[i];
        int4   d = id4[i];
        if (d.x >= 0) atomicAdd(&hist[d.x * NCOPY + copy], __float2uint_rn(p.x * SCALE));
        if (d.y >= 0) atomicAdd(&hist[d.y * NCOPY + copy], __float2uint_rn(p.y * SCALE));
        if (d.z >= 0) atomicAdd(&hist[d.z * NCOPY + copy], __float2uint_rn(p.z * SCALE));
        if (d.w >= 0) atomicAdd(&hist[d.w * NCOPY + copy], __float2uint_rn(p.w * SCALE));
    }
    __syncthreads();

    // Reduce 32 copies per bin; rotated reads -> bank (j+t)&31 distinct per lane.
    if (t < NADMIN) {
        unsigned int s = 0u;
        #pragma unroll
        for (int j = 0; j < NCOPY; ++j) s += hist[t * NCOPY + ((j + t) & 31)];
        Spart[((size_t)b * SEG_BLOCKS + blockIdx.x) * NADMIN + t] = s;
    }
}

// ---------------------------------------------------------------------------
// Pass 2: R[b][a] = census / (sum_blocks Spart / SCALE + eps).
// Exact u64 integer sum, fixed order; plain stores; deterministic.
// grid = NBATCH, block = NADMIN
// ---------------------------------------------------------------------------
__global__ __launch_bounds__(NADMIN) void reduce_kernel(
    const unsigned int* __restrict__ Spart,
    const float* __restrict__ census,
    float* __restrict__ R)
{
    const int b = blockIdx.x;
    const int a = threadIdx.x;
    const unsigned int* base = Spart + (size_t)b * SEG_BLOCKS * NADMIN + a;
    unsigned long long total = 0ull;
    #pragma unroll 8
    for (int j = 0; j < SEG_BLOCKS; ++j) total += base[j * NADMIN];
    float S = (float)((double)total * (1.0 / SCALE));
    R[b * NADMIN + a] = census[b * NADMIN + a] / (S + EPSILON);
}

// ---------------------------------------------------------------------------
// Pass 3: out = valid ? p * R[b][id] : p   (unchanged; passed 7 rounds)
// grid = (128, NBATCH), block = 256
// ---------------------------------------------------------------------------
__global__ __launch_bounds__(256) void apply_kernel(
    const float* __restrict__ P,
    const int* __restrict__ ids,
    const float* __restrict__ R,
    float* __restrict__ out)
{
    __shared__ float s_R[NADMIN];
    const int b = blockIdx.y;
    const int t = threadIdx.x;
    if (t < NADMIN) s_R[t] = R[b * NADMIN + t];
    __syncthreads();

    const float4* __restrict__ p4  = (const float4*)(P   + (size_t)b * NPIX);
    const int4*   __restrict__ id4 = (const int4*)  (ids + (size_t)b * NPIX);
    float4* __restrict__ o4 = (float4*)(out + (size_t)b * NPIX);
    const int nvec = NPIX / 4;
    const int stride = gridDim.x * blockDim.x;

    for (int i = blockIdx.x * blockDim.x + t; i < nvec; i += stride) {
        float4 p = p4[i];
        int4   d = id4[i];
        float4 o;
        o.x = (d.x >= 0) ? p.x * s_R[d.x] : p.x;
        o.y = (d.y >= 0) ? p.y * s_R[d.y] : p.y;
        o.z = (d.z >= 0) ? p.z * s_R[d.z] : p.z;
        o.w = (d.w >= 0) ? p.w * s_R[d.w] : p.w;
        o4[i] = o;
    }
}

extern "C" void kernel_launch(void* const* d_in, const int* in_sizes, int n_in,
                              void* d_out, int out_size, void* d_ws, size_t ws_size,
                              hipStream_t stream)
{
    const float* P      = (const float*)d_in[0];   // (B,1,H,W) f32
    const int*   ids    = (const int*)d_in[1];     // (B,H,W) i32
    const float* census = (const float*)d_in[2];   // (B,A) f32
    float* out = (float*)d_out;

    unsigned int* Spart = (unsigned int*)d_ws;                 // (B,64,A) u32 = 1 MB
    float* R = (float*)(Spart + (size_t)NBATCH * SEG_BLOCKS * NADMIN);  // (B,A)

    segsum_kernel<<<dim3(SEG_BLOCKS, NBATCH), dim3(SEG_THREADS), 0, stream>>>(P, ids, Spart);
    reduce_kernel<<<dim3(NBATCH), dim3(NADMIN), 0, stream>>>(Spart, census, R);
    apply_kernel<<<dim3(128, NBATCH), dim3(256), 0, stream>>>(P, ids, R, out);
}

// Round 12
// 78.249 us; speedup vs baseline: 23.4352x; 1.0139x over previous
//
#include <hip/hip_runtime.h>

#define EPSILON 1e-6f
#define NADMIN 256
#define NBATCH 16
#define NPIX (1024 * 1024)    // H*W per batch
#define SEG_BLOCKS 64         // segsum blocks per batch
#define SEG_THREADS 512
#define NCOPY 8               // histogram copies (lane&7)
#define HSTRIDE 257
#define UNROLL 4
#define SCALE 65536.0f        // fixed-point scale (p in [0,1))

// ---------------------------------------------------------------------------
// FINAL STRUCTURE (measured 75.0 us total, r9; restored after r10/r11 nulls).
// Segsum is bound by the gfx950 LDS-atomic pipe (~110 cyc per scattered
// wave64 ds_add_u32, ~0.6 lanes/cyc) — proven invariant to banking (r11:
// conflicts=0, no gain), copy-spreading (r9), occupancy/MLP (r4), and f32
// CAS removal (r7: the one real win, 82->47 us). Apply runs at ~8 TB/s
// effective (L3-backed fabric ceiling). Reduce is 2 us. Floor = 47+2+25.
// ---------------------------------------------------------------------------

// Pass 1: per-batch partial segment sums, fixed-point u32, native ds_add_u32.
// grid = (SEG_BLOCKS, NBATCH), block = 512 -> 8 iters/thread.
__global__ __launch_bounds__(SEG_THREADS) void segsum_kernel(
    const float* __restrict__ P,
    const int* __restrict__ ids,
    unsigned int* __restrict__ Spart)
{
    __shared__ unsigned int hist[NCOPY * HSTRIDE];   // ~8.2 KB
    const int b = blockIdx.y;
    const int t = threadIdx.x;

    for (int i = t; i < NCOPY * HSTRIDE; i += SEG_THREADS) hist[i] = 0u;
    __syncthreads();

    unsigned int* __restrict__ h = hist + (t & (NCOPY - 1)) * HSTRIDE;

    const float4* __restrict__ p4  = (const float4*)(P   + (size_t)b * NPIX);
    const int4*   __restrict__ id4 = (const int4*)  (ids + (size_t)b * NPIX);
    const int nvec = NPIX / 4;                      // 262144
    const int stride = gridDim.x * blockDim.x;      // 32768

    int i = blockIdx.x * blockDim.x + t;
    for (; i + (UNROLL - 1) * stride < nvec; i += UNROLL * stride) {
        float4 p[UNROLL];
        int4   d[UNROLL];
        #pragma unroll
        for (int u = 0; u < UNROLL; ++u) {          // issue all loads first
            p[u] = p4[i + u * stride];
            d[u] = id4[i + u * stride];
        }
        #pragma unroll
        for (int u = 0; u < UNROLL; ++u) {          // native ds_add_u32
            if (d[u].x >= 0) atomicAdd(&h[d[u].x], __float2uint_rn(p[u].x * SCALE));
            if (d[u].y >= 0) atomicAdd(&h[d[u].y], __float2uint_rn(p[u].y * SCALE));
            if (d[u].z >= 0) atomicAdd(&h[d[u].z], __float2uint_rn(p[u].z * SCALE));
            if (d[u].w >= 0) atomicAdd(&h[d[u].w], __float2uint_rn(p[u].w * SCALE));
        }
    }
    for (; i < nvec; i += stride) {                 // tail (empty here)
        float4 p = p4[i];
        int4   d = id4[i];
        if (d.x >= 0) atomicAdd(&h[d.x], __float2uint_rn(p.x * SCALE));
        if (d.y >= 0) atomicAdd(&h[d.y], __float2uint_rn(p.y * SCALE));
        if (d.z >= 0) atomicAdd(&h[d.z], __float2uint_rn(p.z * SCALE));
        if (d.w >= 0) atomicAdd(&h[d.w], __float2uint_rn(p.w * SCALE));
    }
    __syncthreads();

    // Per-block total <= 16384 px * 2^16 = 2^30: u32-safe across copies.
    if (t < NADMIN) {
        unsigned int s = 0u;
        #pragma unroll
        for (int c = 0; c < NCOPY; ++c) s += hist[c * HSTRIDE + t];
        Spart[((size_t)b * SEG_BLOCKS + blockIdx.x) * NADMIN + t] = s;
    }
}

// Pass 2: R[b][a] = census / (sum_blocks Spart / SCALE + eps).
// Exact u64 integer sum, fixed order; plain stores; replay-deterministic.
// grid = NBATCH, block = NADMIN
__global__ __launch_bounds__(NADMIN) void reduce_kernel(
    const unsigned int* __restrict__ Spart,
    const float* __restrict__ census,
    float* __restrict__ R)
{
    const int b = blockIdx.x;
    const int a = threadIdx.x;
    const unsigned int* base = Spart + (size_t)b * SEG_BLOCKS * NADMIN + a;
    unsigned long long total = 0ull;
    #pragma unroll 8
    for (int j = 0; j < SEG_BLOCKS; ++j) total += base[j * NADMIN];
    float S = (float)((double)total * (1.0 / SCALE));
    R[b * NADMIN + a] = census[b * NADMIN + a] / (S + EPSILON);
}

// Pass 3: out = valid ? p * R[b][id] : p   (fabric-bound, ~8 TB/s effective)
// grid = (128, NBATCH), block = 256
__global__ __launch_bounds__(256) void apply_kernel(
    const float* __restrict__ P,
    const int* __restrict__ ids,
    const float* __restrict__ R,
    float* __restrict__ out)
{
    __shared__ float s_R[NADMIN];
    const int b = blockIdx.y;
    const int t = threadIdx.x;
    if (t < NADMIN) s_R[t] = R[b * NADMIN + t];
    __syncthreads();

    const float4* __restrict__ p4  = (const float4*)(P   + (size_t)b * NPIX);
    const int4*   __restrict__ id4 = (const int4*)  (ids + (size_t)b * NPIX);
    float4* __restrict__ o4 = (float4*)(out + (size_t)b * NPIX);
    const int nvec = NPIX / 4;
    const int stride = gridDim.x * blockDim.x;

    for (int i = blockIdx.x * blockDim.x + t; i < nvec; i += stride) {
        float4 p = p4[i];
        int4   d = id4[i];
        float4 o;
        o.x = (d.x >= 0) ? p.x * s_R[d.x] : p.x;
        o.y = (d.y >= 0) ? p.y * s_R[d.y] : p.y;
        o.z = (d.z >= 0) ? p.z * s_R[d.z] : p.z;
        o.w = (d.w >= 0) ? p.w * s_R[d.w] : p.w;
        o4[i] = o;
    }
}

extern "C" void kernel_launch(void* const* d_in, const int* in_sizes, int n_in,
                              void* d_out, int out_size, void* d_ws, size_t ws_size,
                              hipStream_t stream)
{
    const float* P      = (const float*)d_in[0];   // (B,1,H,W) f32
    const int*   ids    = (const int*)d_in[1];     // (B,H,W) i32
    const float* census = (const float*)d_in[2];   // (B,A) f32
    float* out = (float*)d_out;

    unsigned int* Spart = (unsigned int*)d_ws;                 // (B,64,A) u32 = 1 MB
    float* R = (float*)(Spart + (size_t)NBATCH * SEG_BLOCKS * NADMIN);  // (B,A)

    segsum_kernel<<<dim3(SEG_BLOCKS, NBATCH), dim3(SEG_THREADS), 0, stream>>>(P, ids, Spart);
    reduce_kernel<<<dim3(NBATCH), dim3(NADMIN), 0, stream>>>(Spart, census, R);
    apply_kernel<<<dim3(128, NBATCH), dim3(256), 0, stream>>>(P, ids, R, out);
}